// Round 1
// baseline (396.075 us; speedup 1.0000x reference)
//
#include <hip/hip_runtime.h>
#include <hip/hip_bf16.h>
#include <cstddef>

#define DM 512
#define DK 64
#define BB 4
#define SS 4096
#define NR (BB*SS)   // 16384 total rows

// ---------------- QKV projection ----------------
// grid 512 blocks x 256 threads; each block does 32 rows of x.
// x tile staged in LDS (64 KB); each wave computes 8 rows x 192 cols.
__global__ __launch_bounds__(256) void qkv_proj(
    const float* __restrict__ x,
    const float* __restrict__ wq, const float* __restrict__ bq,
    const float* __restrict__ wk, const float* __restrict__ bk,
    const float* __restrict__ wv, const float* __restrict__ bv,
    float* __restrict__ Q, float* __restrict__ K, float* __restrict__ V)
{
    __shared__ float xs[32 * DM];   // 64 KB
    const int tid  = threadIdx.x;
    const int row0 = blockIdx.x * 32;

    // coalesced float4 load of the x tile
    const float4* xg  = (const float4*)(x + (size_t)row0 * DM);
    float4*       xs4 = (float4*)xs;
    #pragma unroll
    for (int i = 0; i < 16; ++i) xs4[tid + i * 256] = xg[tid + i * 256];
    __syncthreads();

    const int w    = tid >> 6;    // wave 0..3 -> rows w*8..w*8+7
    const int lane = tid & 63;    // output column within each 64-wide matrix

    float acc[3][8];
    #pragma unroll
    for (int c = 0; c < 3; ++c)
        #pragma unroll
        for (int r = 0; r < 8; ++r) acc[c][r] = 0.0f;

    const float* wp[3] = {wq, wk, wv};

    for (int kc = 0; kc < DM / 4; ++kc) {
        float4 xv[8];
        #pragma unroll
        for (int r = 0; r < 8; ++r)
            xv[r] = *(const float4*)&xs[(w * 8 + r) * DM + kc * 4]; // wave-broadcast
        #pragma unroll
        for (int c = 0; c < 3; ++c) {
            #pragma unroll
            for (int kk = 0; kk < 4; ++kk) {
                const float wv_ = wp[c][(kc * 4 + kk) * DK + lane];
                #pragma unroll
                for (int r = 0; r < 8; ++r) {
                    const float xr = (kk == 0) ? xv[r].x : (kk == 1) ? xv[r].y
                                   : (kk == 2) ? xv[r].z : xv[r].w;
                    acc[c][r] = fmaf(xr, wv_, acc[c][r]);
                }
            }
        }
    }

    float*       op[3] = {Q, K, V};
    const float* bp[3] = {bq, bk, bv};
    #pragma unroll
    for (int c = 0; c < 3; ++c) {
        const float bias = bp[c][lane];
        #pragma unroll
        for (int r = 0; r < 8; ++r) {
            const size_t orow = (size_t)(row0 + w * 8 + r);
            op[c][orow * DK + lane] = acc[c][r] + bias;
        }
    }
}

// ---------------- flash attention (fp32 VALU) ----------------
// One thread per q-row. K/V tiles (64 rows) staged in LDS.
// Online softmax with defer-max threshold 8 (rescale path ~never taken).
// grid (16, 4, sigma); sigma splits the KV range; partials merged later.
__global__ __launch_bounds__(256) void attn(
    const float* __restrict__ Q, const float* __restrict__ K,
    const float* __restrict__ V,
    float* __restrict__ Opart, float* __restrict__ Mpart,
    float* __restrict__ Lpart, float* __restrict__ out, int sigma)
{
    __shared__ float Ks[64 * DK];  // 16 KB
    __shared__ float Vs[64 * DK];  // 16 KB

    const int tid  = threadIdx.x;
    const int qt   = blockIdx.x;
    const int b    = blockIdx.y;
    const int ci   = blockIdx.z;
    const int klen  = SS / sigma;
    const int kbase = ci * klen;

    const int srow = qt * 256 + tid;
    const int row  = b * SS + srow;

    // q row into registers, pre-scaled by 1/sqrt(64)
    float q[DK];
    {
        const float4* qp = (const float4*)(Q + (size_t)row * DK);
        #pragma unroll
        for (int i = 0; i < 16; ++i) {
            float4 v4 = qp[i];
            q[i * 4 + 0] = v4.x * 0.125f;
            q[i * 4 + 1] = v4.y * 0.125f;
            q[i * 4 + 2] = v4.z * 0.125f;
            q[i * 4 + 3] = v4.w * 0.125f;
        }
    }

    float m = -1e30f, l = 0.0f;
    float o[DK];
    #pragma unroll
    for (int d = 0; d < DK; ++d) o[d] = 0.0f;

    for (int t = 0; t < klen / 64; ++t) {
        __syncthreads();
        const float4* kg  = (const float4*)(K + ((size_t)b * SS + kbase + t * 64) * DK);
        const float4* vg  = (const float4*)(V + ((size_t)b * SS + kbase + t * 64) * DK);
        float4*       ks4 = (float4*)Ks;
        float4*       vs4 = (float4*)Vs;
        #pragma unroll
        for (int i = 0; i < 4; ++i) {
            ks4[tid + i * 256] = kg[tid + i * 256];
            vs4[tid + i * 256] = vg[tid + i * 256];
        }
        __syncthreads();

        for (int j = 0; j < 64; ++j) {
            const float* kr = &Ks[j * DK];
            float s = 0.0f;
            #pragma unroll
            for (int d4 = 0; d4 < 16; ++d4) {
                const float4 kk = *(const float4*)&kr[d4 * 4]; // wave-broadcast
                s = fmaf(q[d4 * 4 + 0], kk.x, s);
                s = fmaf(q[d4 * 4 + 1], kk.y, s);
                s = fmaf(q[d4 * 4 + 2], kk.z, s);
                s = fmaf(q[d4 * 4 + 3], kk.w, s);
            }
            if (s - m > 8.0f) {           // defer-max: ~never after warmup
                const float corr = __expf(m - s);
                m = s;
                l *= corr;
                #pragma unroll
                for (int d = 0; d < DK; ++d) o[d] *= corr;
            }
            const float p = __expf(s - m);
            l += p;
            const float* vr = &Vs[j * DK];
            #pragma unroll
            for (int d4 = 0; d4 < 16; ++d4) {
                const float4 vv = *(const float4*)&vr[d4 * 4]; // wave-broadcast
                o[d4 * 4 + 0] = fmaf(p, vv.x, o[d4 * 4 + 0]);
                o[d4 * 4 + 1] = fmaf(p, vv.y, o[d4 * 4 + 1]);
                o[d4 * 4 + 2] = fmaf(p, vv.z, o[d4 * 4 + 2]);
                o[d4 * 4 + 3] = fmaf(p, vv.w, o[d4 * 4 + 3]);
            }
        }
    }

    if (sigma == 1) {
        const float inv = 1.0f / l;
        float* op = out + (size_t)row * DK;
        #pragma unroll
        for (int d = 0; d < DK; ++d) op[d] = o[d] * inv;
    } else {
        Mpart[(size_t)ci * NR + row] = m;
        Lpart[(size_t)ci * NR + row] = l;
        float* op = Opart + ((size_t)ci * NR + row) * DK;
        #pragma unroll
        for (int d = 0; d < DK; ++d) op[d] = o[d];
    }
}

// ---------------- merge KV-split partials ----------------
__global__ __launch_bounds__(256) void attn_reduce(
    const float* __restrict__ Opart, const float* __restrict__ Mpart,
    const float* __restrict__ Lpart, float* __restrict__ out, int sigma)
{
    const int e   = blockIdx.x * 256 + threadIdx.x;  // < NR*DK
    const int row = e >> 6;
    const int d   = e & 63;

    float M = -1e30f;
    for (int i = 0; i < sigma; ++i) M = fmaxf(M, Mpart[(size_t)i * NR + row]);
    float L = 0.0f, O = 0.0f;
    for (int i = 0; i < sigma; ++i) {
        const float wgt = __expf(Mpart[(size_t)i * NR + row] - M);
        L = fmaf(wgt, Lpart[(size_t)i * NR + row], L);
        O = fmaf(wgt, Opart[((size_t)i * NR + row) * DK + d], O);
    }
    out[e] = O / L;
}

extern "C" void kernel_launch(void* const* d_in, const int* in_sizes, int n_in,
                              void* d_out, int out_size, void* d_ws, size_t ws_size,
                              hipStream_t stream)
{
    const float* x  = (const float*)d_in[0];
    const float* wq = (const float*)d_in[1];
    const float* bq = (const float*)d_in[2];
    const float* wk = (const float*)d_in[3];
    const float* bk = (const float*)d_in[4];
    const float* wv = (const float*)d_in[5];
    const float* bv = (const float*)d_in[6];

    float* ws = (float*)d_ws;
    const size_t NQ = (size_t)NR * DK;              // 1,048,576 floats per matrix

    float* Q  = ws;
    float* Kb = ws + NQ;
    float* Vb = ws + 2 * NQ;

    // pick the largest KV-split that fits the workspace
    int sigma = 1;
    const int cand[3] = {8, 4, 2};
    for (int i = 0; i < 3; ++i) {
        const int s = cand[i];
        const size_t need = (size_t)(3 + s) * NQ * 4 + (size_t)s * NR * 2 * 4;
        if (need <= ws_size) { sigma = s; break; }
    }

    float* Opart = ws + 3 * NQ;
    float* Mpart = ws + (size_t)(3 + sigma) * NQ;
    float* Lpart = Mpart + (size_t)sigma * NR;

    qkv_proj<<<512, 256, 0, stream>>>(x, wq, bq, wk, bk, wv, bv, Q, Kb, Vb);

    dim3 grid(SS / 256, BB, sigma);
    attn<<<grid, 256, 0, stream>>>(Q, Kb, Vb, Opart, Mpart, Lpart, (float*)d_out, sigma);

    if (sigma > 1)
        attn_reduce<<<(NR * DK) / 256, 256, 0, stream>>>(Opart, Mpart, Lpart,
                                                         (float*)d_out, sigma);
}

// Round 3
// 113.377 us; speedup vs baseline: 3.4934x; 3.4934x over previous
//
#include <hip/hip_runtime.h>
#include <hip/hip_bf16.h>
#include <cstddef>
#include <cstdint>

#define DM 512
#define DK 64
#define BB 4
#define S4 4096
#define NR (BB*S4)      // 16384 rows
#define KVB 64
#define QBLOCK 128      // 4 waves x 32 q-rows
#define LP 72           // LDS row pitch in ushorts (144 B, 16B-aligned, 4-way banks)

typedef float   f32x16 __attribute__((ext_vector_type(16)));
typedef short   bf16x8 __attribute__((ext_vector_type(8)));

// Q pre-scale: 1/sqrt(64) * log2(e)  (softmax runs in exp2 domain)
#define QSCALE 0.18033688011112042f

// ---------------- QKV projection (fp32 compute, bf16 out) ----------------
__global__ __launch_bounds__(256) void qkv_proj(
    const float* __restrict__ x,
    const float* __restrict__ wq, const float* __restrict__ bq,
    const float* __restrict__ wk, const float* __restrict__ bk,
    const float* __restrict__ wv, const float* __restrict__ bv,
    ushort* __restrict__ Qb, ushort* __restrict__ Kb, ushort* __restrict__ Vb)
{
    __shared__ float xs[32 * DM];   // 64 KB
    const int tid  = threadIdx.x;
    const int row0 = blockIdx.x * 32;

    const float4* xg  = (const float4*)(x + (size_t)row0 * DM);
    float4*       xs4 = (float4*)xs;
    #pragma unroll
    for (int i = 0; i < 16; ++i) xs4[tid + i * 256] = xg[tid + i * 256];
    __syncthreads();

    const int w    = tid >> 6;
    const int lane = tid & 63;

    float acc[3][8];
    #pragma unroll
    for (int c = 0; c < 3; ++c)
        #pragma unroll
        for (int r = 0; r < 8; ++r) acc[c][r] = 0.0f;

    const float* wp[3] = {wq, wk, wv};

    for (int kc = 0; kc < DM / 4; ++kc) {
        float4 xv[8];
        #pragma unroll
        for (int r = 0; r < 8; ++r)
            xv[r] = *(const float4*)&xs[(w * 8 + r) * DM + kc * 4];
        #pragma unroll
        for (int c = 0; c < 3; ++c) {
            #pragma unroll
            for (int kk = 0; kk < 4; ++kk) {
                const float wv_ = wp[c][(kc * 4 + kk) * DK + lane];
                #pragma unroll
                for (int r = 0; r < 8; ++r) {
                    const float xr = (kk == 0) ? xv[r].x : (kk == 1) ? xv[r].y
                                   : (kk == 2) ? xv[r].z : xv[r].w;
                    acc[c][r] = fmaf(xr, wv_, acc[c][r]);
                }
            }
        }
    }

    ushort*      op[3] = {Qb, Kb, Vb};
    const float* bp[3] = {bq, bk, bv};
    #pragma unroll
    for (int c = 0; c < 3; ++c) {
        const float bias = bp[c][lane];
        #pragma unroll
        for (int r = 0; r < 8; ++r) {
            const size_t orow = (size_t)(row0 + w * 8 + r);
            float v = acc[c][r] + bias;
            if (c == 0) v *= QSCALE;
            __hip_bfloat16 h = __float2bfloat16(v);
            op[c][orow * DK + lane] = *reinterpret_cast<ushort*>(&h);
        }
    }
}

// ---------------- V transpose: [b][s][dv] -> Vt[b][dv][s] ----------------
__global__ __launch_bounds__(256) void transpose_v(
    const ushort* __restrict__ V, ushort* __restrict__ Vt)
{
    __shared__ ushort t[64 * 72];
    const int tid = threadIdx.x;
    const int s0  = blockIdx.x * 64;
    const int b   = blockIdx.y;
    const int sr  = tid >> 2, c = tid & 3;

    const uint4* src = reinterpret_cast<const uint4*>(
        V + ((size_t)b * S4 + s0 + sr) * DK + c * 16);
    uint4 v0 = src[0], v1 = src[1];
    *reinterpret_cast<uint4*>(&t[sr * 72 + c * 16])     = v0;
    *reinterpret_cast<uint4*>(&t[sr * 72 + c * 16 + 8]) = v1;
    __syncthreads();

    const int dv = tid >> 2;
    alignas(16) ushort o[16];
    #pragma unroll
    for (int i = 0; i < 16; ++i) o[i] = t[(c * 16 + i) * 72 + dv];
    uint4* dst = reinterpret_cast<uint4*>(
        Vt + ((size_t)b * DK + dv) * S4 + s0 + c * 16);
    dst[0] = *reinterpret_cast<const uint4*>(&o[0]);
    dst[1] = *reinterpret_cast<const uint4*>(&o[8]);
}

// ---------------- MFMA flash attention ----------------
// 4 waves x 32 q-rows, KVB=64, swapped QK^T (S^T = K*Q), online exp2 softmax.
// LDS: plain padded [64][LP] layout, reg-staged with next-tile prefetch.
__global__ __launch_bounds__(256, 2) void attn_mfma(
    const ushort* __restrict__ Qb, const ushort* __restrict__ Kb,
    const ushort* __restrict__ Vt,
    float* __restrict__ Opart, float* __restrict__ Mpart,
    float* __restrict__ Lpart, float* __restrict__ out, int sigma)
{
    __shared__ ushort Ks[64 * LP];  // 9216 B
    __shared__ ushort Vs[64 * LP];

    const int tid  = threadIdx.x;
    const int w    = tid >> 6;
    const int lane = tid & 63;
    const int hi   = lane >> 5;
    const int q5   = lane & 31;
    const int b    = blockIdx.y, ci = blockIdx.z;
    const int klen = S4 / sigma, kv0 = ci * klen;
    const int qrow = blockIdx.x * QBLOCK + w * 32 + q5;

    // staging: 512 16B-chunks per matrix, 2 per thread. chunk c: row c>>3, colchunk c&7
    const int c0 = tid, c1 = tid + 256;
    const int r0 = c0 >> 3, cc0 = c0 & 7;
    const int r1 = c1 >> 3, cc1 = c1 & 7;

    // Q fragment (pre-scaled bf16): B-operand, col = q5, k = s*16 + hi*8 + e
    bf16x8 qf[4];
    {
        const ushort* qp = Qb + ((size_t)b * S4 + qrow) * DK;
        #pragma unroll
        for (int s = 0; s < 4; ++s)
            qf[s] = *reinterpret_cast<const bf16x8*>(qp + s * 16 + hi * 8);
    }

    f32x16 oacc0 = {}, oacc1 = {};
    float m = -1e30f, lsum = 0.0f;

    uint4 kreg0, kreg1, vreg0, vreg1;
    auto gload = [&](int t) {
        const ushort* gK = Kb + ((size_t)b * S4 + kv0 + t * KVB) * DK;
        const ushort* gV = Vt + (size_t)b * DK * S4 + (kv0 + t * KVB);
        kreg0 = *reinterpret_cast<const uint4*>(gK + r0 * DK + cc0 * 8);
        kreg1 = *reinterpret_cast<const uint4*>(gK + r1 * DK + cc1 * 8);
        vreg0 = *reinterpret_cast<const uint4*>(gV + (size_t)r0 * S4 + cc0 * 8);
        vreg1 = *reinterpret_cast<const uint4*>(gV + (size_t)r1 * S4 + cc1 * 8);
    };

    const int nt = klen / KVB;
    gload(0);

    for (int t = 0; t < nt; ++t) {
        __syncthreads();   // previous tile's LDS reads complete
        *reinterpret_cast<uint4*>(&Ks[r0 * LP + cc0 * 8]) = kreg0;
        *reinterpret_cast<uint4*>(&Ks[r1 * LP + cc1 * 8]) = kreg1;
        *reinterpret_cast<uint4*>(&Vs[r0 * LP + cc0 * 8]) = vreg0;
        *reinterpret_cast<uint4*>(&Vs[r1 * LP + cc1 * 8]) = vreg1;
        __syncthreads();   // tile ready
        if (t + 1 < nt) gload(t + 1);   // prefetch; latency hides under compute

        #pragma unroll
        for (int sub = 0; sub < 2; ++sub) {
            // ---- QK^T: S^T = K x Q ----
            const int kvr = sub * 32 + q5;
            bf16x8 kf[4];
            #pragma unroll
            for (int s = 0; s < 4; ++s)
                kf[s] = *reinterpret_cast<const bf16x8*>(
                    &Ks[kvr * LP + (2 * s + hi) * 8]);
            f32x16 sacc = {};
            #pragma unroll
            for (int s = 0; s < 4; ++s)
                sacc = __builtin_amdgcn_mfma_f32_32x32x16_bf16(
                    kf[s], qf[s], sacc, 0, 0, 0);

            // ---- online softmax (exp2 domain), defer-max THR=8 ----
            float pmax = sacc[0];
            #pragma unroll
            for (int r = 1; r < 16; ++r) pmax = fmaxf(pmax, sacc[r]);
            pmax = fmaxf(pmax, __shfl_xor(pmax, 32));

            if (__any(pmax > m + 8.0f)) {
                const float mn   = fmaxf(m, pmax);
                const float corr = exp2f(m - mn);
                lsum *= corr;
                #pragma unroll
                for (int r = 0; r < 16; ++r) {
                    const int qq = (r & 3) + 8 * (r >> 2) + 4 * hi;
                    const float cq = __shfl(corr, qq);
                    oacc0[r] *= cq; oacc1[r] *= cq;
                }
                m = mn;
            }

            float p[16];
            float ts = 0.0f;
            #pragma unroll
            for (int r = 0; r < 16; ++r) {
                p[r] = exp2f(sacc[r] - m);
                ts += p[r];
            }
            lsum += ts + __shfl_xor(ts, 32);

            // ---- P -> bf16 PV A-fragments ----
            // wd[2g+k] packs p[4g+2k], p[4g+2k+1]  (kv = {8g+4hi+2k, +1})
            uint32_t wd[8];
            #pragma unroll
            for (int g = 0; g < 4; ++g) {
                #pragma unroll
                for (int k = 0; k < 2; ++k) {
                    __hip_bfloat16 h0 = __float2bfloat16(p[4 * g + 2 * k]);
                    __hip_bfloat16 h1 = __float2bfloat16(p[4 * g + 2 * k + 1]);
                    wd[2 * g + k] = (uint32_t)(*reinterpret_cast<ushort*>(&h0))
                                  | ((uint32_t)(*reinterpret_cast<ushort*>(&h1)) << 16);
                }
            }
            // branchless half-wave exchange: full-wave shfl of pre-selected word
            const uint32_t e0 = __shfl_xor(hi ? wd[0] : wd[2], 32);
            const uint32_t e1 = __shfl_xor(hi ? wd[1] : wd[3], 32);
            const uint32_t e2 = __shfl_xor(hi ? wd[4] : wd[6], 32);
            const uint32_t e3 = __shfl_xor(hi ? wd[5] : wd[7], 32);
            union { uint32_t u[4]; bf16x8 v; } pa0, pa1;
            pa0.u[0] = hi ? e0 : wd[0];   // kv_local {8hi+0,1}
            pa0.u[1] = hi ? e1 : wd[1];
            pa0.u[2] = hi ? wd[2] : e0;   // kv_local {8hi+4,5}
            pa0.u[3] = hi ? wd[3] : e1;
            pa1.u[0] = hi ? e2 : wd[4];
            pa1.u[1] = hi ? e3 : wd[5];
            pa1.u[2] = hi ? wd[6] : e2;
            pa1.u[3] = hi ? wd[7] : e3;

            // ---- PV: O[q][dv] += P x V ----
            #pragma unroll
            for (int h = 0; h < 2; ++h) {
                const int dv = h * 32 + q5;
                #pragma unroll
                for (int tt = 0; tt < 2; ++tt) {
                    const bf16x8 vf = *reinterpret_cast<const bf16x8*>(
                        &Vs[dv * LP + (sub * 4 + tt * 2 + hi) * 8]);
                    if (h == 0)
                        oacc0 = __builtin_amdgcn_mfma_f32_32x32x16_bf16(
                            tt == 0 ? pa0.v : pa1.v, vf, oacc0, 0, 0, 0);
                    else
                        oacc1 = __builtin_amdgcn_mfma_f32_32x32x16_bf16(
                            tt == 0 ? pa0.v : pa1.v, vf, oacc1, 0, 0, 0);
                }
            }
        }
    }

    // ---- epilogue ----
    if (sigma == 1) {
        #pragma unroll
        for (int r = 0; r < 16; ++r) {
            const int qq = (r & 3) + 8 * (r >> 2) + 4 * hi;
            const float lq  = __shfl(lsum, qq);
            const float inv = 1.0f / lq;
            const size_t row = (size_t)b * S4 + blockIdx.x * QBLOCK + w * 32 + qq;
            out[row * DK + q5]      = oacc0[r] * inv;
            out[row * DK + 32 + q5] = oacc1[r] * inv;
        }
    } else {
        if (hi == 0) {
            const size_t row = (size_t)b * S4 + qrow;
            Mpart[(size_t)ci * NR + row] = m;
            Lpart[(size_t)ci * NR + row] = lsum;
        }
        #pragma unroll
        for (int r = 0; r < 16; ++r) {
            const int qq = (r & 3) + 8 * (r >> 2) + 4 * hi;
            const size_t row = (size_t)b * S4 + blockIdx.x * QBLOCK + w * 32 + qq;
            float* op = Opart + ((size_t)ci * NR + row) * DK;
            op[q5]      = oacc0[r];
            op[32 + q5] = oacc1[r];
        }
    }
}

// ---------------- merge KV-split partials (exp2 domain) ----------------
__global__ __launch_bounds__(256) void attn_reduce(
    const float* __restrict__ Opart, const float* __restrict__ Mpart,
    const float* __restrict__ Lpart, float* __restrict__ out, int sigma)
{
    const int e   = blockIdx.x * 256 + threadIdx.x;
    const int row = e >> 6;
    const int d   = e & 63;

    float M = -1e30f;
    for (int i = 0; i < sigma; ++i) M = fmaxf(M, Mpart[(size_t)i * NR + row]);
    float L = 0.0f, O = 0.0f;
    for (int i = 0; i < sigma; ++i) {
        const float wgt = exp2f(Mpart[(size_t)i * NR + row] - M);
        L = fmaf(wgt, Lpart[(size_t)i * NR + row], L);
        O = fmaf(wgt, Opart[((size_t)i * NR + row) * DK + d], O);
    }
    out[e] = O / L;
}

extern "C" void kernel_launch(void* const* d_in, const int* in_sizes, int n_in,
                              void* d_out, int out_size, void* d_ws, size_t ws_size,
                              hipStream_t stream)
{
    const float* x  = (const float*)d_in[0];
    const float* wq = (const float*)d_in[1];
    const float* bq = (const float*)d_in[2];
    const float* wk = (const float*)d_in[3];
    const float* bk = (const float*)d_in[4];
    const float* wv = (const float*)d_in[5];
    const float* bv = (const float*)d_in[6];

    char* ws = (char*)d_ws;
    const size_t MB2 = (size_t)NR * DK * 2;   // 2 MB per bf16 matrix

    ushort* Qb = (ushort*)(ws);
    ushort* Kb = (ushort*)(ws + MB2);
    ushort* Vb = (ushort*)(ws + 2 * MB2);
    ushort* Vt = (ushort*)(ws + 3 * MB2);

    int sigma = 1;
    const int cand[2] = {4, 2};
    for (int i = 0; i < 2; ++i) {
        const int s = cand[i];
        const size_t need = 4 * MB2 + (size_t)s * ((size_t)NR * DK * 4 + (size_t)NR * 8);
        if (need <= ws_size) { sigma = s; break; }
    }

    float* Opart = (float*)(ws + 4 * MB2);
    float* Mpart = (float*)(ws + 4 * MB2 + (size_t)sigma * NR * DK * 4);
    float* Lpart = Mpart + (size_t)sigma * NR;

    qkv_proj<<<NR / 32, 256, 0, stream>>>(x, wq, bq, wk, bk, wv, bv, Qb, Kb, Vb);
    transpose_v<<<dim3(S4 / 64, BB), 256, 0, stream>>>(Vb, Vt);

    dim3 grid(S4 / QBLOCK, BB, sigma);
    attn_mfma<<<grid, 256, 0, stream>>>(Qb, Kb, Vt, Opart, Mpart, Lpart,
                                        (float*)d_out, sigma);

    if (sigma > 1)
        attn_reduce<<<(NR * DK) / 256, 256, 0, stream>>>(Opart, Mpart, Lpart,
                                                         (float*)d_out, sigma);
}